// Round 6
// baseline (155.808 us; speedup 1.0000x reference)
//
#include <hip/hip_runtime.h>
#include <math.h>

#define CH_STRIDE (512 * 512)

// f32 DCT matrix = float32(float64 0.5*cos((2x+1)u*pi/16), row0 /sqrt2) — matches asarray(D, float32)
static constexpr float DMc[8][8] = {
  { 0.35355339059327373f, 0.35355339059327373f, 0.35355339059327373f, 0.35355339059327373f,
    0.35355339059327373f, 0.35355339059327373f, 0.35355339059327373f, 0.35355339059327373f},
  { 0.49039264020161522f, 0.41573480615127262f, 0.27778511650980111f, 0.09754516100806413f,
   -0.09754516100806413f,-0.27778511650980111f,-0.41573480615127262f,-0.49039264020161522f},
  { 0.46193976625564337f, 0.19134171618254489f,-0.19134171618254489f,-0.46193976625564337f,
   -0.46193976625564337f,-0.19134171618254489f, 0.19134171618254489f, 0.46193976625564337f},
  { 0.41573480615127262f,-0.09754516100806413f,-0.49039264020161522f,-0.27778511650980111f,
    0.27778511650980111f, 0.49039264020161522f, 0.09754516100806413f,-0.41573480615127262f},
  { 0.35355339059327373f,-0.35355339059327373f,-0.35355339059327373f, 0.35355339059327373f,
    0.35355339059327373f,-0.35355339059327373f,-0.35355339059327373f, 0.35355339059327373f},
  { 0.27778511650980111f,-0.49039264020161522f, 0.09754516100806413f, 0.41573480615127262f,
   -0.41573480615127262f,-0.09754516100806413f, 0.49039264020161522f,-0.27778511650980111f},
  { 0.19134171618254489f,-0.46193976625564337f, 0.46193976625564337f,-0.19134171618254489f,
   -0.19134171618254489f, 0.46193976625564337f,-0.46193976625564337f, 0.19134171618254489f},
  { 0.09754516100806413f,-0.27778511650980111f, 0.41573480615127262f,-0.49039264020161522f,
    0.49039264020161522f,-0.41573480615127262f, 0.27778511650980111f,-0.09754516100806413f},
};

// q = float32(table) * 0.5f — exact halves. [0..63]=Y[u][v], [64..127]=C.
static constexpr float QTABc[128] = {
   8.0f,  5.5f,  5.0f,  8.0f, 12.0f, 20.0f, 25.5f, 30.5f,
   6.0f,  6.0f,  7.0f,  9.5f, 13.0f, 29.0f, 30.0f, 27.5f,
   7.0f,  6.5f,  8.0f, 12.0f, 20.0f, 28.5f, 34.5f, 28.0f,
   7.0f,  8.5f, 11.0f, 14.5f, 25.5f, 43.5f, 40.0f, 31.0f,
   9.0f, 11.0f, 18.5f, 28.0f, 34.0f, 54.5f, 51.5f, 38.5f,
  12.0f, 17.5f, 27.5f, 32.0f, 40.5f, 52.0f, 56.5f, 46.0f,
  24.5f, 32.0f, 39.0f, 43.5f, 51.5f, 60.5f, 60.0f, 50.5f,
  36.0f, 46.0f, 47.5f, 49.0f, 56.0f, 50.0f, 51.5f, 49.5f,

   8.5f,  9.0f, 12.0f, 23.5f, 49.5f, 49.5f, 49.5f, 49.5f,
   9.0f, 10.5f, 13.0f, 33.0f, 49.5f, 49.5f, 49.5f, 49.5f,
  12.0f, 13.0f, 28.0f, 49.5f, 49.5f, 49.5f, 49.5f, 49.5f,
  23.5f, 33.0f, 49.5f, 49.5f, 49.5f, 49.5f, 49.5f, 49.5f,
  49.5f, 49.5f, 49.5f, 49.5f, 49.5f, 49.5f, 49.5f, 49.5f,
  49.5f, 49.5f, 49.5f, 49.5f, 49.5f, 49.5f, 49.5f, 49.5f,
  49.5f, 49.5f, 49.5f, 49.5f, 49.5f, 49.5f, 49.5f, 49.5f,
  49.5f, 49.5f, 49.5f, 49.5f, 49.5f, 49.5f, 49.5f, 49.5f,
};

// correctly-rounded f32 ops, no contraction — each maps to one numpy C op
__device__ __forceinline__ float fm(float a, float b) { return __fmul_rn(a, b); }
__device__ __forceinline__ float fa(float a, float b) { return __fadd_rn(a, b); }
__device__ __forceinline__ float fs(float a, float b) { return __fsub_rn(a, b); }
__device__ __forceinline__ float fd(float a, float b) { return __fdiv_rn(a, b); }

// One workgroup = 3 waves (192 threads), TWO 32x32 tiles processed sequentially (grid 2048).
// R0-R5 record: stall is ~21-23us in every structure while occupancy sits at ~2.3 waves/SIMD
// regardless of static limits → per-wave ILP, not residency, sets VALUBusy. This version:
//   - einsum loads FULLY HOISTED into registers (16x ds_read_b128 / 32x ds_read_b64 issued
//     as one independent batch, then the dependent VALU chain) — R0-style, minus R0's
//     dead lanes and extra issue. VGPR ~110 (4 waves/SIMD) is a fine trade at 2.3 resident.
//   - 2 tiles/block: halves block boundaries → amortizes per-block unhidden head/tail.
//   - stage1/5 extra-quad work rebalanced 16/16/32 across waves (was 64 on wave 0).
// Arithmetic chains untouched from the verified kernel (hoisting loads has no FP effect).
// NOTE (R2): never pass min-waves-per-EU=8 — it forces VGPR=32 and catastrophic spill.
// NOTE (R4/R5): packed FP32 (v_pk_*_f32) does NOT double FP32 throughput on CDNA4
// (157.3 TF spec == scalar FMA rate); VOP3P halves inst count but doubles cycles/inst.
__global__ __launch_bounds__(192, 4)
void jpeg_kernel(const float* __restrict__ x, float* __restrict__ out) {
  const int tid  = threadIdx.x;
  const int lane = tid & 63;
  const int wav  = tid >> 6;

  __shared__ __align__(16) float Ys[32][36];    // centered Y, then recon y_r (in-place per wave)
  __shared__ __align__(16) float Cb[16][20];    // subsampled -128, then recon cbm (in-place)
  __shared__ __align__(16) float Cr[16][20];
  __shared__ __align__(16) float Cq[24][8][10]; // quantized coefs; stride 10 → rows 8B-aligned (b64)

  // Extra-quad assignment (quads 192..255, 64 total), balanced 16/16/32 with shfl-pairing kept:
  // each wave's chunk is contiguous and 16-aligned, so lane l ↔ l^8 spans row-parity pairs.
  const int eq = (wav == 0) ? (lane < 16 ? 192 + lane : -1)
               : (wav == 1) ? (lane < 16 ? 208 + lane : -1)
                            : (lane < 32 ? 224 + lane : -1);

  // Task mapping (tile-independent): blk = tid>>3 (0..15 Y, 16..19 Cb, 20..23 Cr), j = tid&7.
  const int  blk = tid >> 3;
  const int  j   = tid & 7;
  const bool isY = blk < 16;
  const float* src;   // 8x8 block base in LDS
  float*       wdst;  // recon row dest (aliases src buffer; same-wave in-order → safe)
  int ld;
  const float* qr = QTABc + j * 8;
  if (isY) {
    const int by = blk >> 2, bx = blk & 3;
    src = &Ys[by * 8][bx * 8];  wdst = &Ys[by * 8 + j][bx * 8];  ld = 36;
  } else if (blk < 20) {
    const int c = blk - 16, cy = c >> 1, cx = c & 1;
    src = &Cb[cy * 8][cx * 8];  wdst = &Cb[cy * 8 + j][cx * 8];  ld = 20;  qr += 64;
  } else {
    const int c = blk - 20, cy = c >> 1, cx = c & 1;
    src = &Cr[cy * 8][cx * 8];  wdst = &Cr[cy * 8 + j][cx * 8];  ld = 20;  qr += 64;
  }

  for (int tt = 0; tt < 2; ++tt) {
    const int tile = (blockIdx.x << 1) + tt;   // 0..4095
    const int b  = tile >> 8;                  // image 0..15
    const int qq = tile & 255;
    const int row0 = (qq >> 4) << 5;           // 32-px tile row
    const int col0 = (qq & 15) << 5;

    // ---------------- Stage 1: load, clip, *255, color convert (strict f32, no FMA) ----------------
    auto stage1 = [&](int qd) {
      const int pr = qd >> 3;
      const int pc = (qd & 7) << 2;
      const size_t ib = ((((size_t)b * 3) * 512 + (size_t)(row0 + pr)) * 512) + (size_t)(col0 + pc);
      float4 rv = *(const float4*)(x + ib);
      float4 gv = *(const float4*)(x + ib + CH_STRIDE);
      float4 bv = *(const float4*)(x + ib + 2 * CH_STRIDE);
      float xr[4] = {rv.x, rv.y, rv.z, rv.w};
      float xg[4] = {gv.x, gv.y, gv.z, gv.w};
      float xb[4] = {bv.x, bv.y, bv.z, bv.w};
      float yo[4], cbv[4], crv[4];
#pragma unroll
      for (int i = 0; i < 4; ++i) {
        float r  = fm(fminf(fmaxf(xr[i], 0.0f), 1.0f), 255.0f);
        float g  = fm(fminf(fmaxf(xg[i], 0.0f), 1.0f), 255.0f);
        float bb = fm(fminf(fmaxf(xb[i], 0.0f), 1.0f), 255.0f);
        float y  = fa(fa(fm(0.299f, r), fm(0.587f, g)), fm(0.114f, bb));
        yo[i]  = fs(y, 128.0f);
        cbv[i] = fa(fa(fs(fm(-0.168736f, r), fm(0.331264f, g)), fm(0.5f, bb)), 128.0f);
        crv[i] = fa(fs(fs(fm(0.5f, r), fm(0.418688f, g)), fm(0.081312f, bb)), 128.0f);
      }
      *(float4*)&Ys[pr][pc] = make_float4(yo[0], yo[1], yo[2], yo[3]);

      // chroma 2x2 mean — pairwise (c00+c01)+(c10+c11), exact /4 as *0.25f (power-of-2, bit-equal)
      float cbh0 = fa(cbv[0], cbv[1]), cbh1 = fa(cbv[2], cbv[3]);
      float crh0 = fa(crv[0], crv[1]), crh1 = fa(crv[2], crv[3]);
      float pcb0 = __shfl_xor(cbh0, 8, 64);   // partner = adjacent pixel row, same cols (same wave)
      float pcb1 = __shfl_xor(cbh1, 8, 64);
      float pcr0 = __shfl_xor(crh0, 8, 64);
      float pcr1 = __shfl_xor(crh1, 8, 64);
      if (((qd >> 3) & 1) == 0) {             // even pixel row: owns the 2x2 output
        const int ii = pr >> 1, jc = pc >> 1;
        Cb[ii][jc]     = fs(fm(fa(cbh0, pcb0), 0.25f), 128.0f);
        Cb[ii][jc + 1] = fs(fm(fa(cbh1, pcb1), 0.25f), 128.0f);
        Cr[ii][jc]     = fs(fm(fa(crh0, pcr0), 0.25f), 128.0f);
        Cr[ii][jc + 1] = fs(fm(fa(crh1, pcr1), 0.25f), 128.0f);
      }
    };
    stage1(tid);
    if (eq >= 0) stage1(eq);
    __syncthreads();

    // ======= einsum1 'bhwxy,ux,vy->bhwuv' — full register hoist, bit-identical term order =======
    // Load all 64 block elements first (independent ds_read batch), then:
    // t0[8xx+yy] = fl(blk[xx][yy]*D[j][xx]); per v, 4 chains s[v][l], term sequence m=0..15:
    // s[v][l] += t0[4m+l]*D[v][(4m+l)&7]; coef = fl(fl(s0+s1)+fl(s2+s3)). Exactly the verified
    // scalar sequence — only load scheduling changed (no FP effect).
    {
      float rd[64];
      {
        const float* srow = src;
#pragma unroll
        for (int xx = 0; xx < 8; ++xx) {
          float4 aq = *(const float4*)(srow);
          float4 bq = *(const float4*)(srow + 4);
          srow += ld;
          rd[xx * 8 + 0] = aq.x; rd[xx * 8 + 1] = aq.y; rd[xx * 8 + 2] = aq.z; rd[xx * 8 + 3] = aq.w;
          rd[xx * 8 + 4] = bq.x; rd[xx * 8 + 5] = bq.y; rd[xx * 8 + 6] = bq.z; rd[xx * 8 + 7] = bq.w;
        }
      }
      float dj[8];
#pragma unroll
      for (int xx = 0; xx < 8; ++xx) dj[xx] = DMc[j][xx];
      float t0[64];
#pragma unroll
      for (int xx = 0; xx < 8; ++xx)
#pragma unroll
        for (int yy = 0; yy < 8; ++yy)
          t0[xx * 8 + yy] = fm(rd[xx * 8 + yy], dj[xx]);

      float s[8][4];
#pragma unroll
      for (int v = 0; v < 8; ++v) { s[v][0] = 0.0f; s[v][1] = 0.0f; s[v][2] = 0.0f; s[v][3] = 0.0f; }
#pragma unroll
      for (int xx = 0; xx < 8; ++xx) {
        const int k = xx * 8;
#pragma unroll
        for (int v = 0; v < 8; ++v) {
          s[v][0] = fa(s[v][0], fm(t0[k + 0], DMc[v][0]));   // m = 2*xx
          s[v][1] = fa(s[v][1], fm(t0[k + 1], DMc[v][1]));
          s[v][2] = fa(s[v][2], fm(t0[k + 2], DMc[v][2]));
          s[v][3] = fa(s[v][3], fm(t0[k + 3], DMc[v][3]));
          s[v][0] = fa(s[v][0], fm(t0[k + 4], DMc[v][4]));   // m = 2*xx+1
          s[v][1] = fa(s[v][1], fm(t0[k + 5], DMc[v][5]));
          s[v][2] = fa(s[v][2], fm(t0[k + 6], DMc[v][6]));
          s[v][3] = fa(s[v][3], fm(t0[k + 7], DMc[v][7]));
        }
      }
      float* cq = &Cq[blk][j][0];
#pragma unroll
      for (int v = 0; v < 8; ++v) {
        float coef = fa(fa(s[v][0], s[v][1]), fa(s[v][2], s[v][3]));   // hadd tree
        float qv = qr[v];
        cq[v] = fm(rintf(fd(coef, qv)), qv);                           // round half-even, f32 div
      }
    }

    // Cq[blk] producers and consumers are the SAME wave: per-wave LDS ops complete in order —
    // compiler fence + drain of our own ds ops, no block barrier.
    asm volatile("s_waitcnt lgkmcnt(0)" ::: "memory");

    // ======= einsum2 'bhwuv,ux,vy->bhwxy' — full register hoist, bit-identical term order =======
    // Load all 64 coefs (32x ds_read_b64 batch), then per u: t2r[v]=fl(coef[u][v]*D[u][x=j]);
    // per yy, v=0..7 in order: acc[yy] += t2r[v]*D[v][yy] — the verified scalar sequence.
    {
      float tc[64];
      {
        const float* cqb = &Cq[blk][0][0];
#pragma unroll
        for (int u = 0; u < 8; ++u) {
          float2 p0 = *(const float2*)(cqb + u * 10);
          float2 p1 = *(const float2*)(cqb + u * 10 + 2);
          float2 p2 = *(const float2*)(cqb + u * 10 + 4);
          float2 p3 = *(const float2*)(cqb + u * 10 + 6);
          tc[u * 8 + 0] = p0.x; tc[u * 8 + 1] = p0.y;
          tc[u * 8 + 2] = p1.x; tc[u * 8 + 3] = p1.y;
          tc[u * 8 + 4] = p2.x; tc[u * 8 + 5] = p2.y;
          tc[u * 8 + 6] = p3.x; tc[u * 8 + 7] = p3.y;
        }
      }
      float acc[8];
#pragma unroll
      for (int yy = 0; yy < 8; ++yy) acc[yy] = 0.0f;
#pragma unroll
      for (int u = 0; u < 8; ++u) {
        float du = DMc[u][j];
        float t2r[8];
#pragma unroll
        for (int v = 0; v < 8; ++v) t2r[v] = fm(tc[u * 8 + v], du);
#pragma unroll
        for (int yy = 0; yy < 8; ++yy) {
#pragma unroll
          for (int v = 0; v < 8; ++v)
            acc[yy] = fa(acc[yy], fm(t2r[v], DMc[v][yy]));             // sequential, per-term rounding
        }
      }
      float r0[8];
#pragma unroll
      for (int yy = 0; yy < 8; ++yy) {
        float rec = fa(acc[yy], 128.0f);
        r0[yy] = isY ? rec : fs(rec, 128.0f);                          // y_r  /  cbm = cb_u - 128
      }
      *(float4*)(wdst)     = make_float4(r0[0], r0[1], r0[2], r0[3]);
      *(float4*)(wdst + 4) = make_float4(r0[4], r0[5], r0[6], r0[7]);
    }
    __syncthreads();

    // ---------------- Stage 5: upsample, YCbCr->RGB (strict), clip, /255, wrapper ----------------
    auto stage5 = [&](int qd) {
      const int pr = qd >> 3;
      const int pc = (qd & 7) << 2;
      const size_t ib = ((((size_t)b * 3) * 512 + (size_t)(row0 + pr)) * 512) + (size_t)(col0 + pc);
      float4 rv = *(const float4*)(x + ib);          // re-load x (L1/L2-hot)
      float4 gv = *(const float4*)(x + ib + CH_STRIDE);
      float4 bv = *(const float4*)(x + ib + 2 * CH_STRIDE);
      float xr[4] = {rv.x, rv.y, rv.z, rv.w};
      float xg[4] = {gv.x, gv.y, gv.z, gv.w};
      float xb[4] = {bv.x, bv.y, bv.z, bv.w};
      float ro[4], go[4], bo[4];
      const int hr = pr >> 1;
#pragma unroll
      for (int i = 0; i < 4; ++i) {
        float y_r = Ys[pr][pc + i];
        float cbm = Cb[hr][(pc + i) >> 1];
        float crm = Cr[hr][(pc + i) >> 1];
        float r2 = fa(y_r, fm(1.402f, crm));
        float g2 = fs(fs(y_r, fm(0.344136f, cbm)), fm(0.714136f, crm));
        float b2 = fa(y_r, fm(1.772f, cbm));
        float jr = fd(fminf(fmaxf(r2, 0.0f), 255.0f), 255.0f);
        float jg = fd(fminf(fmaxf(g2, 0.0f), 255.0f), 255.0f);
        float jb = fd(fminf(fmaxf(b2, 0.0f), 255.0f), 255.0f);
        ro[i] = fa(xr[i], fs(jr, xr[i]));   // x + (jpeg - x), original unclipped x
        go[i] = fa(xg[i], fs(jg, xg[i]));
        bo[i] = fa(xb[i], fs(jb, xb[i]));
      }
      *(float4*)(out + ib)                 = make_float4(ro[0], ro[1], ro[2], ro[3]);
      *(float4*)(out + ib + CH_STRIDE)     = make_float4(go[0], go[1], go[2], go[3]);
      *(float4*)(out + ib + 2 * CH_STRIDE) = make_float4(bo[0], bo[1], bo[2], bo[3]);
    };
    stage5(tid);
    if (eq >= 0) stage5(eq);

    if (tt == 0) __syncthreads();   // LDS reused by next tile's stage1
  }
}

extern "C" void kernel_launch(void* const* d_in, const int* in_sizes, int n_in,
                              void* d_out, int out_size, void* d_ws, size_t ws_size,
                              hipStream_t stream) {
  const float* x = (const float*)d_in[0];
  float* out = (float*)d_out;
  jpeg_kernel<<<dim3(2048), dim3(192), 0, stream>>>(x, out);
}

// Round 7
// 126.024 us; speedup vs baseline: 1.2363x; 1.2363x over previous
//
#include <hip/hip_runtime.h>
#include <math.h>

#define CH_STRIDE (512 * 512)

// f32 DCT matrix = float32(float64 0.5*cos((2x+1)u*pi/16), row0 /sqrt2) — matches asarray(D, float32)
static constexpr float DMc[8][8] = {
  { 0.35355339059327373f, 0.35355339059327373f, 0.35355339059327373f, 0.35355339059327373f,
    0.35355339059327373f, 0.35355339059327373f, 0.35355339059327373f, 0.35355339059327373f},
  { 0.49039264020161522f, 0.41573480615127262f, 0.27778511650980111f, 0.09754516100806413f,
   -0.09754516100806413f,-0.27778511650980111f,-0.41573480615127262f,-0.49039264020161522f},
  { 0.46193976625564337f, 0.19134171618254489f,-0.19134171618254489f,-0.46193976625564337f,
   -0.46193976625564337f,-0.19134171618254489f, 0.19134171618254489f, 0.46193976625564337f},
  { 0.41573480615127262f,-0.09754516100806413f,-0.49039264020161522f,-0.27778511650980111f,
    0.27778511650980111f, 0.49039264020161522f, 0.09754516100806413f,-0.41573480615127262f},
  { 0.35355339059327373f,-0.35355339059327373f,-0.35355339059327373f, 0.35355339059327373f,
    0.35355339059327373f,-0.35355339059327373f,-0.35355339059327373f, 0.35355339059327373f},
  { 0.27778511650980111f,-0.49039264020161522f, 0.09754516100806413f, 0.41573480615127262f,
   -0.41573480615127262f,-0.09754516100806413f, 0.49039264020161522f,-0.27778511650980111f},
  { 0.19134171618254489f,-0.46193976625564337f, 0.46193976625564337f,-0.19134171618254489f,
   -0.19134171618254489f, 0.46193976625564337f,-0.46193976625564337f, 0.19134171618254489f},
  { 0.09754516100806413f,-0.27778511650980111f, 0.41573480615127262f,-0.49039264020161522f,
    0.49039264020161522f,-0.41573480615127262f, 0.27778511650980111f,-0.09754516100806413f},
};

// q = float32(table) * 0.5f — exact halves. [0..63]=Y[u][v], [64..127]=C.
static constexpr float QTABc[128] = {
   8.0f,  5.5f,  5.0f,  8.0f, 12.0f, 20.0f, 25.5f, 30.5f,
   6.0f,  6.0f,  7.0f,  9.5f, 13.0f, 29.0f, 30.0f, 27.5f,
   7.0f,  6.5f,  8.0f, 12.0f, 20.0f, 28.5f, 34.5f, 28.0f,
   7.0f,  8.5f, 11.0f, 14.5f, 25.5f, 43.5f, 40.0f, 31.0f,
   9.0f, 11.0f, 18.5f, 28.0f, 34.0f, 54.5f, 51.5f, 38.5f,
  12.0f, 17.5f, 27.5f, 32.0f, 40.5f, 52.0f, 56.5f, 46.0f,
  24.5f, 32.0f, 39.0f, 43.5f, 51.5f, 60.5f, 60.0f, 50.5f,
  36.0f, 46.0f, 47.5f, 49.0f, 56.0f, 50.0f, 51.5f, 49.5f,

   8.5f,  9.0f, 12.0f, 23.5f, 49.5f, 49.5f, 49.5f, 49.5f,
   9.0f, 10.5f, 13.0f, 33.0f, 49.5f, 49.5f, 49.5f, 49.5f,
  12.0f, 13.0f, 28.0f, 49.5f, 49.5f, 49.5f, 49.5f, 49.5f,
  23.5f, 33.0f, 49.5f, 49.5f, 49.5f, 49.5f, 49.5f, 49.5f,
  49.5f, 49.5f, 49.5f, 49.5f, 49.5f, 49.5f, 49.5f, 49.5f,
  49.5f, 49.5f, 49.5f, 49.5f, 49.5f, 49.5f, 49.5f, 49.5f,
  49.5f, 49.5f, 49.5f, 49.5f, 49.5f, 49.5f, 49.5f, 49.5f,
  49.5f, 49.5f, 49.5f, 49.5f, 49.5f, 49.5f, 49.5f, 49.5f,
};

// correctly-rounded f32 ops, no contraction — each maps to one numpy C op
__device__ __forceinline__ float fm(float a, float b) { return __fmul_rn(a, b); }
__device__ __forceinline__ float fa(float a, float b) { return __fadd_rn(a, b); }
__device__ __forceinline__ float fs(float a, float b) { return __fsub_rn(a, b); }
__device__ __forceinline__ float fd(float a, float b) { return __fdiv_rn(a, b); }

// One workgroup = 6 waves (384 threads) = TWO independent 32x32-tile half-blocks, each
// running the verified R3 3-wave pipeline on its own tile + own LDS copy. Rationale:
// occupancy pinned at ~3 resident WGs/CU across all configs (R0/R1/R3/R4: 27-31% at
// wildly different LDS/VGPR) → residency is per-WORKGROUP-capped, not resource-capped.
// More waves per WG = more resident waves: 3 WGs/CU x 6 waves = 18 waves/CU (vs 9.6).
// Per-thread code, arithmetic order, and sync structure are UNCHANGED from R3 per half
// (half 1's local waves 0..2 are physical waves 3..5 — shfl pairs and the same-wave Cq
// dependency hold).
// NOTE (R2): never request 8 waves/EU in launch_bounds (forces VGPR=32, catastrophic spill).
// NOTE (R6): never hold two 64-float arrays live (rd+t0) — allocator spills to scratch.
// NOTE (R4/R5): v_pk_*_f32 does NOT double FP32 throughput on CDNA4 (157.3 TF == scalar rate).
__global__ __launch_bounds__(384, 2)
void jpeg_kernel(const float* __restrict__ x, float* __restrict__ out) {
  const int tidg = threadIdx.x;        // 0..383
  const int h    = tidg >> 7 >= 1 ? (tidg >= 192) : 0; // half id (0: tid<192, 1: tid>=192)
  const int tid  = tidg - (h ? 192 : 0);               // half-local tid 0..191

  __shared__ __align__(16) float Ys[2][32][36];    // centered Y, then recon y_r (in-place per wave)
  __shared__ __align__(16) float Cb[2][16][20];    // subsampled -128, then recon cbm (in-place)
  __shared__ __align__(16) float Cr[2][16][20];
  __shared__ __align__(16) float Cq[2][24][8][10]; // quantized coefs; stride 10 → rows 8B-aligned

  const int tile = (blockIdx.x << 1) + h;    // 0..4095
  const int b  = tile >> 8;                  // image 0..15
  const int qq = tile & 255;
  const int row0 = (qq >> 4) << 5;           // 32-px tile row
  const int col0 = (qq & 15) << 5;

  // ---------------- Stage 1: load, clip, *255, color convert (strict f32, no FMA) ----------------
  // quad qd (0..255): pr=qd>>3, pc=(qd&7)*4. Threads handle qd=tid; half-local wave 0 also 192+tid.
  auto stage1 = [&](int qd) {
    const int pr = qd >> 3;
    const int pc = (qd & 7) << 2;
    const size_t ib = ((((size_t)b * 3) * 512 + (size_t)(row0 + pr)) * 512) + (size_t)(col0 + pc);
    float4 rv = *(const float4*)(x + ib);
    float4 gv = *(const float4*)(x + ib + CH_STRIDE);
    float4 bv = *(const float4*)(x + ib + 2 * CH_STRIDE);
    float xr[4] = {rv.x, rv.y, rv.z, rv.w};
    float xg[4] = {gv.x, gv.y, gv.z, gv.w};
    float xb[4] = {bv.x, bv.y, bv.z, bv.w};
    float yo[4], cbv[4], crv[4];
#pragma unroll
    for (int i = 0; i < 4; ++i) {
      float r  = fm(fminf(fmaxf(xr[i], 0.0f), 1.0f), 255.0f);
      float g  = fm(fminf(fmaxf(xg[i], 0.0f), 1.0f), 255.0f);
      float bb = fm(fminf(fmaxf(xb[i], 0.0f), 1.0f), 255.0f);
      float y  = fa(fa(fm(0.299f, r), fm(0.587f, g)), fm(0.114f, bb));
      yo[i]  = fs(y, 128.0f);
      cbv[i] = fa(fa(fs(fm(-0.168736f, r), fm(0.331264f, g)), fm(0.5f, bb)), 128.0f);
      crv[i] = fa(fs(fs(fm(0.5f, r), fm(0.418688f, g)), fm(0.081312f, bb)), 128.0f);
    }
    *(float4*)&Ys[h][pr][pc] = make_float4(yo[0], yo[1], yo[2], yo[3]);

    // chroma 2x2 mean — pairwise (c00+c01)+(c10+c11), exact /4 as *0.25f (power-of-2, bit-equal)
    float cbh0 = fa(cbv[0], cbv[1]), cbh1 = fa(cbv[2], cbv[3]);
    float crh0 = fa(crv[0], crv[1]), crh1 = fa(crv[2], crv[3]);
    float pcb0 = __shfl_xor(cbh0, 8, 64);   // partner = adjacent pixel row, same cols (same wave)
    float pcb1 = __shfl_xor(cbh1, 8, 64);
    float pcr0 = __shfl_xor(crh0, 8, 64);
    float pcr1 = __shfl_xor(crh1, 8, 64);
    if (((qd >> 3) & 1) == 0) {             // even pixel row: owns the 2x2 output
      const int ii = pr >> 1, jc = pc >> 1;
      Cb[h][ii][jc]     = fs(fm(fa(cbh0, pcb0), 0.25f), 128.0f);
      Cb[h][ii][jc + 1] = fs(fm(fa(cbh1, pcb1), 0.25f), 128.0f);
      Cr[h][ii][jc]     = fs(fm(fa(crh0, pcr0), 0.25f), 128.0f);
      Cr[h][ii][jc + 1] = fs(fm(fa(crh1, pcr1), 0.25f), 128.0f);
    }
  };
  stage1(tid);
  if (tid < 64) stage1(192 + tid);        // whole (half-local) wave 0 → shfl pairs stay intact
  __syncthreads();

  // Task mapping: blk = tid>>3 (0..15 Y, 16..19 Cb, 20..23 Cr), j = tid&7 (coef row u / recon row x)
  const int  blk = tid >> 3;
  const int  j   = tid & 7;
  const bool isY = blk < 16;
  const float* src;   // 8x8 block base in LDS
  float*       wdst;  // recon row dest (aliases src buffer; same-wave in-order → safe)
  int ld;
  const float* qr = QTABc + j * 8;
  if (isY) {
    const int by = blk >> 2, bx = blk & 3;
    src = &Ys[h][by * 8][bx * 8];  wdst = &Ys[h][by * 8 + j][bx * 8];  ld = 36;
  } else if (blk < 20) {
    const int c = blk - 16, cy = c >> 1, cx = c & 1;
    src = &Cb[h][cy * 8][cx * 8];  wdst = &Cb[h][cy * 8 + j][cx * 8];  ld = 20;  qr += 64;
  } else {
    const int c = blk - 20, cy = c >> 1, cx = c & 1;
    src = &Cr[h][cy * 8][cx * 8];  wdst = &Cr[h][cy * 8 + j][cx * 8];  ld = 20;  qr += 64;
  }

  // ======= einsum1 'bhwxy,ux,vy->bhwuv' — np c_einsum outstride0_three, SIMD 4-lane =======
  // Register-lean form: per xx row, accumulate m=2xx then m=2xx+1 into s[v][l].
  // Each accumulator s[v][l] receives EXACTLY the original term sequence
  //   m=0..15: fa(s, fm(t0[4m+l], DMc[v][(4m+l)&7]))  with t0[8xx+yy]=fm(blk[xx][yy],DMc[j][xx]),
  // then coef = fa(fa(s0,s1),fa(s2,s3)) (SSE3 hadd tree) — bit-identical.
  {
    float dj[8];
#pragma unroll
    for (int xx = 0; xx < 8; ++xx) dj[xx] = DMc[j][xx];
    float s[8][4];
#pragma unroll
    for (int v = 0; v < 8; ++v) { s[v][0] = 0.0f; s[v][1] = 0.0f; s[v][2] = 0.0f; s[v][3] = 0.0f; }
    const float* srow = src;
#pragma unroll
    for (int xx = 0; xx < 8; ++xx) {
      float4 aq = *(const float4*)(srow);
      float4 bq = *(const float4*)(srow + 4);
      srow += ld;
      float t0r[8] = { fm(aq.x, dj[xx]), fm(aq.y, dj[xx]), fm(aq.z, dj[xx]), fm(aq.w, dj[xx]),
                       fm(bq.x, dj[xx]), fm(bq.y, dj[xx]), fm(bq.z, dj[xx]), fm(bq.w, dj[xx]) };
#pragma unroll
      for (int v = 0; v < 8; ++v) {
        s[v][0] = fa(s[v][0], fm(t0r[0], DMc[v][0]));   // m = 2*xx
        s[v][1] = fa(s[v][1], fm(t0r[1], DMc[v][1]));
        s[v][2] = fa(s[v][2], fm(t0r[2], DMc[v][2]));
        s[v][3] = fa(s[v][3], fm(t0r[3], DMc[v][3]));
        s[v][0] = fa(s[v][0], fm(t0r[4], DMc[v][4]));   // m = 2*xx+1
        s[v][1] = fa(s[v][1], fm(t0r[5], DMc[v][5]));
        s[v][2] = fa(s[v][2], fm(t0r[6], DMc[v][6]));
        s[v][3] = fa(s[v][3], fm(t0r[7], DMc[v][7]));
      }
    }
    float* cq = &Cq[h][blk][j][0];
#pragma unroll
    for (int v = 0; v < 8; ++v) {
      float coef = fa(fa(s[v][0], s[v][1]), fa(s[v][2], s[v][3]));   // hadd tree
      float qv = qr[v];
      cq[v] = fm(rintf(fd(coef, qv)), qv);                           // round half-even, f32 div
    }
  }

  // Cq[h][blk] producers and consumers are the SAME wave (blk>>3 == half-local wave id):
  // per-wave LDS ops complete in order — compiler fence + drain of our own ds ops, no barrier.
  asm volatile("s_waitcnt lgkmcnt(0)" ::: "memory");

  // ======= einsum2 'bhwuv,ux,vy->bhwxy' — per-element scalar chain, u outer / v inner =======
  // Register-lean: per u, t2r[v]=fm(Cq[u][v],DMc[u][j]); each acc[yy] gets (u,v) terms in the
  // original lexicographic order — bit-identical.
  {
    float acc[8];
#pragma unroll
    for (int yy = 0; yy < 8; ++yy) acc[yy] = 0.0f;
    const float* cqb = &Cq[h][blk][0][0];
#pragma unroll
    for (int u = 0; u < 8; ++u) {
      float du = DMc[u][j];
      float t2r[8];
#pragma unroll
      for (int v = 0; v < 8; ++v) t2r[v] = fm(cqb[u * 10 + v], du);
#pragma unroll
      for (int yy = 0; yy < 8; ++yy) {
#pragma unroll
        for (int v = 0; v < 8; ++v)
          acc[yy] = fa(acc[yy], fm(t2r[v], DMc[v][yy]));             // sequential, per-term rounding
      }
    }
    float r0[8];
#pragma unroll
    for (int yy = 0; yy < 8; ++yy) {
      float rec = fa(acc[yy], 128.0f);
      r0[yy] = isY ? rec : fs(rec, 128.0f);                          // y_r  /  cbm = cb_u - 128
    }
    *(float4*)(wdst)     = make_float4(r0[0], r0[1], r0[2], r0[3]);
    *(float4*)(wdst + 4) = make_float4(r0[4], r0[5], r0[6], r0[7]);
  }
  __syncthreads();

  // ---------------- Stage 5: upsample, YCbCr->RGB (strict), clip, /255, wrapper ----------------
  auto stage5 = [&](int qd) {
    const int pr = qd >> 3;
    const int pc = (qd & 7) << 2;
    const size_t ib = ((((size_t)b * 3) * 512 + (size_t)(row0 + pr)) * 512) + (size_t)(col0 + pc);
    float4 rv = *(const float4*)(x + ib);          // re-load x (L1/L2-hot)
    float4 gv = *(const float4*)(x + ib + CH_STRIDE);
    float4 bv = *(const float4*)(x + ib + 2 * CH_STRIDE);
    float xr[4] = {rv.x, rv.y, rv.z, rv.w};
    float xg[4] = {gv.x, gv.y, gv.z, gv.w};
    float xb[4] = {bv.x, bv.y, bv.z, bv.w};
    float ro[4], go[4], bo[4];
    const int hr = pr >> 1;
#pragma unroll
    for (int i = 0; i < 4; ++i) {
      float y_r = Ys[h][pr][pc + i];
      float cbm = Cb[h][hr][(pc + i) >> 1];
      float crm = Cr[h][hr][(pc + i) >> 1];
      float r2 = fa(y_r, fm(1.402f, crm));
      float g2 = fs(fs(y_r, fm(0.344136f, cbm)), fm(0.714136f, crm));
      float b2 = fa(y_r, fm(1.772f, cbm));
      float jr = fd(fminf(fmaxf(r2, 0.0f), 255.0f), 255.0f);
      float jg = fd(fminf(fmaxf(g2, 0.0f), 255.0f), 255.0f);
      float jb = fd(fminf(fmaxf(b2, 0.0f), 255.0f), 255.0f);
      ro[i] = fa(xr[i], fs(jr, xr[i]));   // x + (jpeg - x), original unclipped x
      go[i] = fa(xg[i], fs(jg, xg[i]));
      bo[i] = fa(xb[i], fs(jb, xb[i]));
    }
    *(float4*)(out + ib)                 = make_float4(ro[0], ro[1], ro[2], ro[3]);
    *(float4*)(out + ib + CH_STRIDE)     = make_float4(go[0], go[1], go[2], go[3]);
    *(float4*)(out + ib + 2 * CH_STRIDE) = make_float4(bo[0], bo[1], bo[2], bo[3]);
  };
  stage5(tid);
  if (tid < 64) stage5(192 + tid);
}

extern "C" void kernel_launch(void* const* d_in, const int* in_sizes, int n_in,
                              void* d_out, int out_size, void* d_ws, size_t ws_size,
                              hipStream_t stream) {
  const float* x = (const float*)d_in[0];
  float* out = (float*)d_out;
  jpeg_kernel<<<dim3(2048), dim3(384), 0, stream>>>(x, out);
}

// Round 9
// 122.261 us; speedup vs baseline: 1.2744x; 1.0308x over previous
//
#include <hip/hip_runtime.h>
#include <math.h>

#define CH_STRIDE (512 * 512)

// f32 DCT matrix = float32(float64 0.5*cos((2x+1)u*pi/16), row0 /sqrt2) — matches asarray(D, float32)
static constexpr float DMc[8][8] = {
  { 0.35355339059327373f, 0.35355339059327373f, 0.35355339059327373f, 0.35355339059327373f,
    0.35355339059327373f, 0.35355339059327373f, 0.35355339059327373f, 0.35355339059327373f},
  { 0.49039264020161522f, 0.41573480615127262f, 0.27778511650980111f, 0.09754516100806413f,
   -0.09754516100806413f,-0.27778511650980111f,-0.41573480615127262f,-0.49039264020161522f},
  { 0.46193976625564337f, 0.19134171618254489f,-0.19134171618254489f,-0.46193976625564337f,
   -0.46193976625564337f,-0.19134171618254489f, 0.19134171618254489f, 0.46193976625564337f},
  { 0.41573480615127262f,-0.09754516100806413f,-0.49039264020161522f,-0.27778511650980111f,
    0.27778511650980111f, 0.49039264020161522f, 0.09754516100806413f,-0.41573480615127262f},
  { 0.35355339059327373f,-0.35355339059327373f,-0.35355339059327373f, 0.35355339059327373f,
    0.35355339059327373f,-0.35355339059327373f,-0.35355339059327373f, 0.35355339059327373f},
  { 0.27778511650980111f,-0.49039264020161522f, 0.09754516100806413f, 0.41573480615127262f,
   -0.41573480615127262f,-0.09754516100806413f, 0.49039264020161522f,-0.27778511650980111f},
  { 0.19134171618254489f,-0.46193976625564337f, 0.46193976625564337f,-0.19134171618254489f,
   -0.19134171618254489f, 0.46193976625564337f,-0.46193976625564337f, 0.19134171618254489f},
  { 0.09754516100806413f,-0.27778511650980111f, 0.41573480615127262f,-0.49039264020161522f,
    0.49039264020161522f,-0.41573480615127262f, 0.27778511650980111f,-0.09754516100806413f},
};

// q = float32(table) * 0.5f — exact halves. [0..63]=Y[u][v], [64..127]=C.
static constexpr float QTABc[128] = {
   8.0f,  5.5f,  5.0f,  8.0f, 12.0f, 20.0f, 25.5f, 30.5f,
   6.0f,  6.0f,  7.0f,  9.5f, 13.0f, 29.0f, 30.0f, 27.5f,
   7.0f,  6.5f,  8.0f, 12.0f, 20.0f, 28.5f, 34.5f, 28.0f,
   7.0f,  8.5f, 11.0f, 14.5f, 25.5f, 43.5f, 40.0f, 31.0f,
   9.0f, 11.0f, 18.5f, 28.0f, 34.0f, 54.5f, 51.5f, 38.5f,
  12.0f, 17.5f, 27.5f, 32.0f, 40.5f, 52.0f, 56.5f, 46.0f,
  24.5f, 32.0f, 39.0f, 43.5f, 51.5f, 60.5f, 60.0f, 50.5f,
  36.0f, 46.0f, 47.5f, 49.0f, 56.0f, 50.0f, 51.5f, 49.5f,

   8.5f,  9.0f, 12.0f, 23.5f, 49.5f, 49.5f, 49.5f, 49.5f,
   9.0f, 10.5f, 13.0f, 33.0f, 49.5f, 49.5f, 49.5f, 49.5f,
  12.0f, 13.0f, 28.0f, 49.5f, 49.5f, 49.5f, 49.5f, 49.5f,
  23.5f, 33.0f, 49.5f, 49.5f, 49.5f, 49.5f, 49.5f, 49.5f,
  49.5f, 49.5f, 49.5f, 49.5f, 49.5f, 49.5f, 49.5f, 49.5f,
  49.5f, 49.5f, 49.5f, 49.5f, 49.5f, 49.5f, 49.5f, 49.5f,
  49.5f, 49.5f, 49.5f, 49.5f, 49.5f, 49.5f, 49.5f, 49.5f,
  49.5f, 49.5f, 49.5f, 49.5f, 49.5f, 49.5f, 49.5f, 49.5f,
};

// correctly-rounded f32 ops, no contraction — each maps to one numpy C op
__device__ __forceinline__ float fm(float a, float b) { return __fmul_rn(a, b); }
__device__ __forceinline__ float fa(float a, float b) { return __fadd_rn(a, b); }
__device__ __forceinline__ float fs(float a, float b) { return __fsub_rn(a, b); }
__device__ __forceinline__ float fd(float a, float b) { return __fdiv_rn(a, b); }

// One workgroup = one 32x32 pixel tile = 3 waves (192 threads). R3 structure (verified,
// 45.4us) with ONE arithmetic change:
//   einsum2 exact product sharing — fl(x*-c)=-fl(x*c) and fa(s,-p)=fs(s,p) are IEEE-exact,
//   and per u only 22 distinct |D[v][yy]| products exist (row0: a; row4: a; rows 2/6: c,d;
//   odd rows: q1..q4). Each acc[yy] chain receives its (u,v)-lexicographic terms as fa/fs
//   of the shared product — bit-identical, -336 VALU mults/thread (~14% of issue).
// Cq handoff stays IN LDS with the lgkmcnt fence (R3-proven).
// NOTE (R8): __shfl-based Cq exchange FAILED correctness (absmax 1.0) — mechanism
//   unidentified (suspect branch-cloned einsum under divergent exec + bpermute). Do not
//   retry register exchange without an isolated A/B test.
// NOTE (R2): never request 8 waves/EU in launch_bounds (forces VGPR=32, catastrophic spill).
// NOTE (R6): never hold two 64-float local arrays live (allocator spills to scratch).
// NOTE (R4/R5): v_pk_*_f32 does NOT double FP32 throughput on CDNA4 (157.3 TF == scalar rate).
__global__ __launch_bounds__(192, 4)
void jpeg_kernel(const float* __restrict__ x, float* __restrict__ out) {
  const int tid = threadIdx.x;
  const int q  = blockIdx.x;           // 0..4095
  const int b  = q >> 8;               // image 0..15
  const int qq = q & 255;
  const int row0 = (qq >> 4) << 5;     // 32-px tile row
  const int col0 = (qq & 15) << 5;

  __shared__ __align__(16) float Ys[32][36];   // centered Y, then recon y_r (in-place per wave)
  __shared__ __align__(16) float Cb[16][20];   // subsampled -128, then recon cbm (in-place)
  __shared__ __align__(16) float Cr[16][20];
  __shared__ __align__(16) float Cq[24][8][9]; // quantized coefs [blk][u][v] (stride 9)

  // ---------------- Stage 1: load, clip, *255, color convert (strict f32, no FMA) ----------------
  auto stage1 = [&](int qd) {
    const int pr = qd >> 3;
    const int pc = (qd & 7) << 2;
    const size_t ib = ((((size_t)b * 3) * 512 + (size_t)(row0 + pr)) * 512) + (size_t)(col0 + pc);
    float4 rv = *(const float4*)(x + ib);
    float4 gv = *(const float4*)(x + ib + CH_STRIDE);
    float4 bv = *(const float4*)(x + ib + 2 * CH_STRIDE);
    float xr[4] = {rv.x, rv.y, rv.z, rv.w};
    float xg[4] = {gv.x, gv.y, gv.z, gv.w};
    float xb[4] = {bv.x, bv.y, bv.z, bv.w};
    float yo[4], cbv[4], crv[4];
#pragma unroll
    for (int i = 0; i < 4; ++i) {
      float r  = fm(fminf(fmaxf(xr[i], 0.0f), 1.0f), 255.0f);
      float g  = fm(fminf(fmaxf(xg[i], 0.0f), 1.0f), 255.0f);
      float bb = fm(fminf(fmaxf(xb[i], 0.0f), 1.0f), 255.0f);
      float y  = fa(fa(fm(0.299f, r), fm(0.587f, g)), fm(0.114f, bb));
      yo[i]  = fs(y, 128.0f);
      cbv[i] = fa(fa(fs(fm(-0.168736f, r), fm(0.331264f, g)), fm(0.5f, bb)), 128.0f);
      crv[i] = fa(fs(fs(fm(0.5f, r), fm(0.418688f, g)), fm(0.081312f, bb)), 128.0f);
    }
    *(float4*)&Ys[pr][pc] = make_float4(yo[0], yo[1], yo[2], yo[3]);

    // chroma 2x2 mean — pairwise (c00+c01)+(c10+c11), exact /4 as *0.25f (power-of-2, bit-equal)
    float cbh0 = fa(cbv[0], cbv[1]), cbh1 = fa(cbv[2], cbv[3]);
    float crh0 = fa(crv[0], crv[1]), crh1 = fa(crv[2], crv[3]);
    float pcb0 = __shfl_xor(cbh0, 8, 64);   // partner = adjacent pixel row, same cols (same wave)
    float pcb1 = __shfl_xor(cbh1, 8, 64);
    float pcr0 = __shfl_xor(crh0, 8, 64);
    float pcr1 = __shfl_xor(crh1, 8, 64);
    if (((qd >> 3) & 1) == 0) {             // even pixel row: owns the 2x2 output
      const int ii = pr >> 1, jc = pc >> 1;
      Cb[ii][jc]     = fs(fm(fa(cbh0, pcb0), 0.25f), 128.0f);
      Cb[ii][jc + 1] = fs(fm(fa(cbh1, pcb1), 0.25f), 128.0f);
      Cr[ii][jc]     = fs(fm(fa(crh0, pcr0), 0.25f), 128.0f);
      Cr[ii][jc + 1] = fs(fm(fa(crh1, pcr1), 0.25f), 128.0f);
    }
  };
  stage1(tid);
  if (tid < 64) stage1(192 + tid);        // whole wave 0 → shfl pairs stay intact
  __syncthreads();

  // Task mapping: blk = tid>>3 (0..15 Y, 16..19 Cb, 20..23 Cr), j = tid&7 (coef row u / recon row x)
  const int  blk = tid >> 3;
  const int  j   = tid & 7;
  const bool isY = blk < 16;
  const float* src;   // 8x8 block base in LDS
  float*       wdst;  // recon row dest (aliases src buffer; same-wave in-order → safe)
  int ld;
  const float* qr = QTABc + j * 8;
  if (isY) {
    const int by = blk >> 2, bx = blk & 3;
    src = &Ys[by * 8][bx * 8];  wdst = &Ys[by * 8 + j][bx * 8];  ld = 36;
  } else if (blk < 20) {
    const int c = blk - 16, cy = c >> 1, cx = c & 1;
    src = &Cb[cy * 8][cx * 8];  wdst = &Cb[cy * 8 + j][cx * 8];  ld = 20;  qr += 64;
  } else {
    const int c = blk - 20, cy = c >> 1, cx = c & 1;
    src = &Cr[cy * 8][cx * 8];  wdst = &Cr[cy * 8 + j][cx * 8];  ld = 20;  qr += 64;
  }

  // ======= einsum1 'bhwxy,ux,vy->bhwuv' — R3 verbatim =======
  // Each accumulator s[v][l] receives EXACTLY the original term sequence
  //   m=0..15: fa(s, fm(t0[4m+l], DMc[v][(4m+l)&7]))  with t0[8xx+yy]=fm(blk[xx][yy],DMc[j][xx]),
  // then coef = fa(fa(s0,s1),fa(s2,s3)) (SSE3 hadd tree) — bit-identical.
  {
    float dj[8];
#pragma unroll
    for (int xx = 0; xx < 8; ++xx) dj[xx] = DMc[j][xx];
    float s[8][4];
#pragma unroll
    for (int v = 0; v < 8; ++v) { s[v][0] = 0.0f; s[v][1] = 0.0f; s[v][2] = 0.0f; s[v][3] = 0.0f; }
    const float* srow = src;
#pragma unroll
    for (int xx = 0; xx < 8; ++xx) {
      float4 aq = *(const float4*)(srow);
      float4 bq = *(const float4*)(srow + 4);
      srow += ld;
      float t0r[8] = { fm(aq.x, dj[xx]), fm(aq.y, dj[xx]), fm(aq.z, dj[xx]), fm(aq.w, dj[xx]),
                       fm(bq.x, dj[xx]), fm(bq.y, dj[xx]), fm(bq.z, dj[xx]), fm(bq.w, dj[xx]) };
#pragma unroll
      for (int v = 0; v < 8; ++v) {
        s[v][0] = fa(s[v][0], fm(t0r[0], DMc[v][0]));   // m = 2*xx
        s[v][1] = fa(s[v][1], fm(t0r[1], DMc[v][1]));
        s[v][2] = fa(s[v][2], fm(t0r[2], DMc[v][2]));
        s[v][3] = fa(s[v][3], fm(t0r[3], DMc[v][3]));
        s[v][0] = fa(s[v][0], fm(t0r[4], DMc[v][4]));   // m = 2*xx+1
        s[v][1] = fa(s[v][1], fm(t0r[5], DMc[v][5]));
        s[v][2] = fa(s[v][2], fm(t0r[6], DMc[v][6]));
        s[v][3] = fa(s[v][3], fm(t0r[7], DMc[v][7]));
      }
    }
    float* cq = &Cq[blk][j][0];
#pragma unroll
    for (int v = 0; v < 8; ++v) {
      float coef = fa(fa(s[v][0], s[v][1]), fa(s[v][2], s[v][3]));   // hadd tree
      float qv = qr[v];
      cq[v] = fm(rintf(fd(coef, qv)), qv);                           // round half-even, f32 div
    }
  }

  // Cq[blk] producers and consumers are the SAME wave (blk>>3 == tid>>6): per-wave LDS ops
  // complete in order, so no block barrier — just a compiler fence + drain of our own ds ops.
  asm volatile("s_waitcnt lgkmcnt(0)" ::: "memory");

  // ======= einsum2 'bhwuv,ux,vy->bhwxy' — LDS row fetch + exact product sharing =======
  // Scalar reference: per u: t2r[v]=fl(coef[u][v]*D[u][x=j]); per yy, v=0..7 in order:
  //   acc[yy] += t2r[v]*D[v][yy].
  // Products shared via IEEE-exact sign symmetry: D rows have per-row magnitude sets
  //   row0: {a}; row4: {a}*sign; rows 2,6: {c,d}; odd rows: {q1,q2,q3,q4}.
  // Each add below is fa/fs of the product with the exact |D[v][yy]| — bit-identical value
  // and per-chain order to the scalar reference (sign table verified v-row by v-row).
  {
    const float a_ = 0.35355339059327373f;
    const float c_ = 0.46193976625564337f, d_ = 0.19134171618254489f;
    const float q1 = 0.49039264020161522f, q2 = 0.41573480615127262f;
    const float q3 = 0.27778511650980111f, q4 = 0.09754516100806413f;
    float acc[8];
#pragma unroll
    for (int yy = 0; yy < 8; ++yy) acc[yy] = 0.0f;
    const float* cqb = &Cq[blk][0][0];
#pragma unroll
    for (int u = 0; u < 8; ++u) {
      float du = DMc[u][j];
      float t2r[8];
#pragma unroll
      for (int v = 0; v < 8; ++v) t2r[v] = fm(cqb[u * 9 + v], du);
      // 22 shared products
      float P0  = fm(t2r[0], a_);
      float P4  = fm(t2r[4], a_);
      float p2c = fm(t2r[2], c_), p2d = fm(t2r[2], d_);
      float p6c = fm(t2r[6], c_), p6d = fm(t2r[6], d_);
      float p1q1 = fm(t2r[1], q1), p1q2 = fm(t2r[1], q2), p1q3 = fm(t2r[1], q3), p1q4 = fm(t2r[1], q4);
      float p3q1 = fm(t2r[3], q1), p3q2 = fm(t2r[3], q2), p3q3 = fm(t2r[3], q3), p3q4 = fm(t2r[3], q4);
      float p5q1 = fm(t2r[5], q1), p5q2 = fm(t2r[5], q2), p5q3 = fm(t2r[5], q3), p5q4 = fm(t2r[5], q4);
      float p7q1 = fm(t2r[7], q1), p7q2 = fm(t2r[7], q2), p7q3 = fm(t2r[7], q3), p7q4 = fm(t2r[7], q4);
      // add chains, v = 0..7 in order per yy (signs = DMc[v][yy] exactly)
      acc[0]=fa(acc[0],P0); acc[0]=fa(acc[0],p1q1); acc[0]=fa(acc[0],p2c); acc[0]=fa(acc[0],p3q2);
      acc[0]=fa(acc[0],P4); acc[0]=fa(acc[0],p5q3); acc[0]=fa(acc[0],p6d); acc[0]=fa(acc[0],p7q4);

      acc[1]=fa(acc[1],P0); acc[1]=fa(acc[1],p1q2); acc[1]=fa(acc[1],p2d); acc[1]=fs(acc[1],p3q4);
      acc[1]=fs(acc[1],P4); acc[1]=fs(acc[1],p5q1); acc[1]=fs(acc[1],p6c); acc[1]=fs(acc[1],p7q3);

      acc[2]=fa(acc[2],P0); acc[2]=fa(acc[2],p1q3); acc[2]=fs(acc[2],p2d); acc[2]=fs(acc[2],p3q1);
      acc[2]=fs(acc[2],P4); acc[2]=fa(acc[2],p5q4); acc[2]=fa(acc[2],p6c); acc[2]=fa(acc[2],p7q2);

      acc[3]=fa(acc[3],P0); acc[3]=fa(acc[3],p1q4); acc[3]=fs(acc[3],p2c); acc[3]=fs(acc[3],p3q3);
      acc[3]=fa(acc[3],P4); acc[3]=fa(acc[3],p5q2); acc[3]=fs(acc[3],p6d); acc[3]=fs(acc[3],p7q1);

      acc[4]=fa(acc[4],P0); acc[4]=fs(acc[4],p1q4); acc[4]=fs(acc[4],p2c); acc[4]=fa(acc[4],p3q3);
      acc[4]=fa(acc[4],P4); acc[4]=fs(acc[4],p5q2); acc[4]=fs(acc[4],p6d); acc[4]=fa(acc[4],p7q1);

      acc[5]=fa(acc[5],P0); acc[5]=fs(acc[5],p1q3); acc[5]=fs(acc[5],p2d); acc[5]=fa(acc[5],p3q1);
      acc[5]=fs(acc[5],P4); acc[5]=fs(acc[5],p5q4); acc[5]=fa(acc[5],p6c); acc[5]=fs(acc[5],p7q2);

      acc[6]=fa(acc[6],P0); acc[6]=fs(acc[6],p1q2); acc[6]=fa(acc[6],p2d); acc[6]=fa(acc[6],p3q4);
      acc[6]=fs(acc[6],P4); acc[6]=fa(acc[6],p5q1); acc[6]=fs(acc[6],p6c); acc[6]=fa(acc[6],p7q3);

      acc[7]=fa(acc[7],P0); acc[7]=fs(acc[7],p1q1); acc[7]=fa(acc[7],p2c); acc[7]=fs(acc[7],p3q2);
      acc[7]=fa(acc[7],P4); acc[7]=fs(acc[7],p5q3); acc[7]=fa(acc[7],p6d); acc[7]=fs(acc[7],p7q4);
    }
    float r0[8];
#pragma unroll
    for (int yy = 0; yy < 8; ++yy) {
      float rec = fa(acc[yy], 128.0f);
      r0[yy] = isY ? rec : fs(rec, 128.0f);                          // y_r  /  cbm = cb_u - 128
    }
    *(float4*)(wdst)     = make_float4(r0[0], r0[1], r0[2], r0[3]);
    *(float4*)(wdst + 4) = make_float4(r0[4], r0[5], r0[6], r0[7]);
  }
  __syncthreads();

  // ---------------- Stage 5: upsample, YCbCr->RGB (strict), clip, /255, wrapper ----------------
  auto stage5 = [&](int qd) {
    const int pr = qd >> 3;
    const int pc = (qd & 7) << 2;
    const size_t ib = ((((size_t)b * 3) * 512 + (size_t)(row0 + pr)) * 512) + (size_t)(col0 + pc);
    float4 rv = *(const float4*)(x + ib);          // re-load x (L1/L2-hot)
    float4 gv = *(const float4*)(x + ib + CH_STRIDE);
    float4 bv = *(const float4*)(x + ib + 2 * CH_STRIDE);
    float xr[4] = {rv.x, rv.y, rv.z, rv.w};
    float xg[4] = {gv.x, gv.y, gv.z, gv.w};
    float xb[4] = {bv.x, bv.y, bv.z, bv.w};
    float ro[4], go[4], bo[4];
    const int hr = pr >> 1;
#pragma unroll
    for (int i = 0; i < 4; ++i) {
      float y_r = Ys[pr][pc + i];
      float cbm = Cb[hr][(pc + i) >> 1];
      float crm = Cr[hr][(pc + i) >> 1];
      float r2 = fa(y_r, fm(1.402f, crm));
      float g2 = fs(fs(y_r, fm(0.344136f, cbm)), fm(0.714136f, crm));
      float b2 = fa(y_r, fm(1.772f, cbm));
      float jr = fd(fminf(fmaxf(r2, 0.0f), 255.0f), 255.0f);
      float jg = fd(fminf(fmaxf(g2, 0.0f), 255.0f), 255.0f);
      float jb = fd(fminf(fmaxf(b2, 0.0f), 255.0f), 255.0f);
      ro[i] = fa(xr[i], fs(jr, xr[i]));   // x + (jpeg - x), original unclipped x
      go[i] = fa(xg[i], fs(jg, xg[i]));
      bo[i] = fa(xb[i], fs(jb, xb[i]));
    }
    *(float4*)(out + ib)                 = make_float4(ro[0], ro[1], ro[2], ro[3]);
    *(float4*)(out + ib + CH_STRIDE)     = make_float4(go[0], go[1], go[2], go[3]);
    *(float4*)(out + ib + 2 * CH_STRIDE) = make_float4(bo[0], bo[1], bo[2], bo[3]);
  };
  stage5(tid);
  if (tid < 64) stage5(192 + tid);
}

extern "C" void kernel_launch(void* const* d_in, const int* in_sizes, int n_in,
                              void* d_out, int out_size, void* d_ws, size_t ws_size,
                              hipStream_t stream) {
  const float* x = (const float*)d_in[0];
  float* out = (float*)d_out;
  jpeg_kernel<<<dim3(4096), dim3(192), 0, stream>>>(x, out);
}